// Round 6
// baseline (331.464 us; speedup 1.0000x reference)
//
#include <hip/hip_runtime.h>
#include <hip/hip_fp16.h>

// GCN 2-layer inference, N=100000, E=1600000, F_IN=100, H=128, C=47.
// R9: gemm1 tile widen. R8 profile: gemm1 #1 at 55us, VALUBusy 37%, hbm 7.6%,
// occupancy 30% -> issue/latency-bound, dot2 fraction only 73%, W1 re-staged
// by 1563 blocks. New gemm1: 128 nodes/block, 16x16 thread grid, 8 rows x
// 8 cols per thread (64 acc): per kk 64 dot2 + 8 a-b32 + 2 w-b128 (86% dot2),
// LDS 51.2KB -> 3 blocks/CU, grid 782 = 3.05x256 (near single-shot residency).
// CSR build (bucketed, atomic-free), agg1 (fp8), gemm2, agg2 unchanged from
// R8 (326us, absmax 0.0078 vs thr 0.0126).

typedef unsigned int uint32;
typedef float f32x2 __attribute__((ext_vector_type(2)));
typedef __fp16 fp16x2 __attribute__((ext_vector_type(2)));
typedef _Float16 h2v __attribute__((ext_vector_type(2)));

constexpr int N    = 100000;
constexpr int E    = 1600000;
constexpr int FIN  = 100;
constexpr int HD   = 128;
constexpr int C    = 47;
constexpr int C48  = 48;
constexpr int EN_CAP = E + 8 * N;    // padded edge-slot upper bound
constexpr int SCAN_CHUNK = 2048;     // 256 threads * 8
constexpr int NB_SCAN = (N + SCAN_CHUNK - 1) / SCAN_CHUNK;  // 49

// bucketed CSR build
constexpr int NPB   = 512;                          // nodes per bucket (dst>>9)
constexpr int NBUCK = (N + NPB - 1) / NPB;          // 196
constexpr int ABLK  = 400;                          // A-phase blocks
constexpr int EPB   = E / ABLK;                     // 4000 edges per A-block

// ---------- fp8 / fp16 helpers ----------

__device__ __forceinline__ uint32 pack_fp8x4(float x, float y, float z, float w) {
    int r = __builtin_amdgcn_cvt_pk_fp8_f32(x, y, 0, false);   // bytes 0,1
    r = __builtin_amdgcn_cvt_pk_fp8_f32(z, w, r, true);        // bytes 2,3
    return (uint32)r;
}

__device__ __forceinline__ void acc_fp8x4(uint32 v, float& a0, float& a1,
                                          float& a2, float& a3) {
    f32x2 lo = __builtin_amdgcn_cvt_pk_f32_fp8((int)v, false);
    f32x2 hi = __builtin_amdgcn_cvt_pk_f32_fp8((int)v, true);
    a0 += lo[0]; a1 += lo[1]; a2 += hi[0]; a3 += hi[1];
}

__device__ __forceinline__ uint32 pk16(float a, float b) {
    union { fp16x2 h; uint32 u; } x;
    x.h = __builtin_amdgcn_cvt_pkrtz(a, b);    // v_cvt_pkrtz_f16_f32
    return x.u;
}

__device__ __forceinline__ float dot2f(uint32 a, uint32 b, float c) {
#if defined(__has_builtin) && __has_builtin(__builtin_amdgcn_fdot2)
    union { uint32 u; h2v h; } xa, xb; xa.u = a; xb.u = b;
    return __builtin_amdgcn_fdot2(xa.h, xb.h, c, false);
#else
    union { uint32 u; __half2 h; } xa, xb; xa.u = a; xb.u = b;
    float2 fa = __half22float2(xa.h), fb = __half22float2(xb.h);
    return fmaf(fa.y, fb.y, fmaf(fa.x, fb.x, c));
#endif
}

// ---------- bucketed CSR build (no global atomics) ----------

// A1: per-block bucket histogram -> blockhist[bucket][block]
__global__ __launch_bounds__(256) void bucket_hist(const int* __restrict__ dst,
                                                   int* __restrict__ blockhist) {
    __shared__ int h[NBUCK];
    int t = threadIdx.x, blk = blockIdx.x;
    for (int i = t; i < NBUCK; i += 256) h[i] = 0;
    __syncthreads();
    int base = blk * EPB;
    for (int i = t; i < EPB; i += 256)
        atomicAdd(&h[dst[base + i] >> 9], 1);
    __syncthreads();
    for (int i = t; i < NBUCK; i += 256) blockhist[i * ABLK + blk] = h[i];
}

// S1a: per-bucket exclusive scan over the 400 block entries (in place);
// bucket total -> bcnt[b]
__global__ __launch_bounds__(256) void scan_blocks(int* __restrict__ blockhist,
                                                   int* __restrict__ bcnt) {
    __shared__ int sm[512];
    int b = blockIdx.x, t = threadIdx.x;
    int v0 = (t       < ABLK) ? blockhist[b * ABLK + t] : 0;
    int v1 = (t + 256 < ABLK) ? blockhist[b * ABLK + t + 256] : 0;
    sm[t] = v0; sm[t + 256] = v1;
    __syncthreads();
    for (int off = 1; off < 512; off <<= 1) {
        int o0 = sm[t], o1 = sm[t + 256];
        int a0 = (t >= off) ? sm[t - off] : 0;
        int a1 = (t + 256 >= off) ? sm[t + 256 - off] : 0;
        __syncthreads();
        sm[t] = o0 + a0; sm[t + 256] = o1 + a1;
        __syncthreads();
    }
    if (t < ABLK)       blockhist[b * ABLK + t]       = sm[t] - v0;        // exclusive
    if (t + 256 < ABLK) blockhist[b * ABLK + t + 256] = sm[t + 256] - v1;
    if (t == 0) bcnt[b] = sm[ABLK - 1];
}

// S1b: exclusive scan over 196 bucket totals
__global__ void scan_buckets(const int* __restrict__ bcnt, int* __restrict__ bbase) {
    if (threadIdx.x == 0) {
        int run = 0;
        for (int i = 0; i < NBUCK; ++i) { bbase[i] = run; run += bcnt[i]; }
        bbase[NBUCK] = run;   // == E
    }
}

// A2: place packed (dstLocal<<20 | src) into dense bucket segments
__global__ __launch_bounds__(256) void bucket_scatter(const int* __restrict__ ei,
                                                      const int* __restrict__ blockhist,
                                                      const int* __restrict__ bbase,
                                                      uint32* __restrict__ pairs) {
    __shared__ int baseL[NBUCK];
    __shared__ int cur[NBUCK];
    int t = threadIdx.x, blk = blockIdx.x;
    for (int i = t; i < NBUCK; i += 256) {
        baseL[i] = bbase[i] + blockhist[i * ABLK + blk];
        cur[i] = 0;
    }
    __syncthreads();
    int base = blk * EPB;
    for (int i = t; i < EPB; i += 256) {
        int s = ei[base + i];
        int d = ei[E + base + i];
        int b = d >> 9;
        int off = atomicAdd(&cur[b], 1);
        pairs[baseL[b] + off] = (uint32)s | ((uint32)(d & (NPB - 1)) << 20);
    }
}

// B1: per-bucket node degree count (LDS atomics) -> cnt[] (1 = self loop)
__global__ __launch_bounds__(256) void bucket_count(const uint32* __restrict__ pairs,
                                                    const int* __restrict__ bbase,
                                                    int* __restrict__ cnt) {
    __shared__ int c[NPB];
    int b = blockIdx.x, t = threadIdx.x;
    for (int i = t; i < NPB; i += 256) c[i] = 1;   // self loop
    __syncthreads();
    int beg = bbase[b], end = bbase[b + 1];
    for (int i = beg + t; i < end; i += 256)
        atomicAdd(&c[pairs[i] >> 20], 1);
    __syncthreads();
    int node0 = b * NPB;
    for (int i = t; i < NPB; i += 256) {
        int n = node0 + i;
        if (n < N) cnt[n] = c[i];
    }
}

// B2: per-bucket slot placement; ep writes stay inside the bucket's CSR range
__global__ __launch_bounds__(256) void bucket_place(const uint32* __restrict__ pairs,
                                                    const int* __restrict__ bbase,
                                                    const int* __restrict__ rowptr,
                                                    int* __restrict__ ep) {
    __shared__ int rowL[NPB];
    __shared__ int cur[NPB];
    int b = blockIdx.x, t = threadIdx.x;
    int node0 = b * NPB;
    for (int i = t; i < NPB; i += 256) {
        int n = node0 + i;
        rowL[i] = (n < N) ? rowptr[n] : 0;
        cur[i] = 1;   // slot 0 = self loop (written by scan_pass3)
    }
    __syncthreads();
    int beg = bbase[b], end = bbase[b + 1];
    for (int i = beg + t; i < end; i += 256) {
        uint32 p = pairs[i];
        int dl = p >> 20;
        int slot = atomicAdd(&cur[dl], 1);
        ep[rowL[dl] + slot] = (int)(p & 0xFFFFF);
    }
}

// ---------- global scan over node capacities ----------

// sums CAPACITIES: cap = deg rounded up to multiple of 8
__global__ void scan_pass1(const int* __restrict__ cnt, int* __restrict__ partials) {
    int t = threadIdx.x, b = blockIdx.x;
    int base = b * SCAN_CHUNK + t * 8;
    int s = 0;
#pragma unroll
    for (int i = 0; i < 8; ++i) {
        int idx = base + i;
        if (idx < N) s += (cnt[idx] + 7) & ~7;
    }
    __shared__ int sm[256];
    sm[t] = s;
    __syncthreads();
    for (int off = 128; off > 0; off >>= 1) {
        if (t < off) sm[t] += sm[t + off];
        __syncthreads();
    }
    if (t == 0) partials[b] = sm[0];
}

__global__ void scan_pass2(const int* __restrict__ partials, int* __restrict__ pscan,
                           int* __restrict__ rowptr) {
    if (threadIdx.x == 0) {
        int run = 0;
        for (int i = 0; i < NB_SCAN; ++i) { pscan[i] = run; run += partials[i]; }
        rowptr[N] = run;   // padded total, <= E + 8N
    }
}

// rowptr (cap-based) + dinv + self-loop slot + pad slots (src=N -> zero row)
__global__ void scan_pass3(const int* __restrict__ cnt, const int* __restrict__ pscan,
                           int* __restrict__ rowptr, float* __restrict__ dinv,
                           int* __restrict__ ep) {
    int t = threadIdx.x, b = blockIdx.x;
    int base = b * SCAN_CHUNK + t * 8;
    int v[8];
    int s = 0;
#pragma unroll
    for (int i = 0; i < 8; ++i) {
        int idx = base + i;
        v[i] = (idx < N) ? cnt[idx] : 0;
        s += (v[i] + 7) & ~7;
    }
    __shared__ int sm[256];
    sm[t] = s;
    __syncthreads();
    for (int off = 1; off < 256; off <<= 1) {
        int tv = (t >= off) ? sm[t - off] : 0;
        __syncthreads();
        sm[t] += tv;
        __syncthreads();
    }
    int excl = sm[t] - s + pscan[b];
#pragma unroll
    for (int i = 0; i < 8; ++i) {
        int idx = base + i;
        if (idx < N) {
            int cap = (v[i] + 7) & ~7;
            rowptr[idx] = excl;
            ep[excl] = idx;                  // self loop at slot 0
            dinv[idx] = rsqrtf((float)v[i]); // true degree (>=1)
            for (int k = v[i]; k < cap; ++k) ep[excl + k] = N;  // pads -> zero row
            excl += cap;
        }
    }
}

// ---------- GEMM1: xw8[N+1,32 dwords] fp8 = dinv[n] * (x[N,100] @ W1[100,128]) ----------
// 128 nodes/block, 16x16 thread grid, 8 rows x 8 cols per thread.
// Per kk: 64 dot2 + 8 a-b32 (4 distinct addrs/wave, 2-way free) + 2 w-b128.
// LDS 51.2KB -> 3 blocks/CU; grid 782 ~ 3.05x256.

__global__ __launch_bounds__(256) void gemm1(const float* __restrict__ x,
                                             const float* __restrict__ W1,
                                             const float* __restrict__ dinv,
                                             uint32* __restrict__ xw8) {
    __shared__ uint32 sW[50 * 128];    // 25.6 KB
    __shared__ uint32 sX[128 * 50];    // 25.6 KB
    int tx = threadIdx.x;
    size_t node0 = (size_t)blockIdx.x * 128;

    for (int i = tx; i < 50 * 128; i += 256) {
        int kk = i >> 7, c = i & 127;
        sW[i] = pk16(W1[(2 * kk) * HD + c], W1[(2 * kk + 1) * HD + c]);
    }
    for (int i = tx; i < 128 * 50; i += 256) {
        int row = i / 50, kk = i - row * 50;
        size_t node = node0 + row;
        float2 ab = make_float2(0.f, 0.f);
        if (node < (size_t)N)
            ab = ((const float2*)(x + node * FIN))[kk];   // 8B aligned (400B rows)
        sX[i] = pk16(ab.x, ab.y);
    }
    __syncthreads();

    int c0 = (tx & 15) * 8;        // 0..120
    int r0 = (tx >> 4) * 8;        // 0..120
    float acc[8][8];
#pragma unroll
    for (int i = 0; i < 8; ++i)
#pragma unroll
        for (int j = 0; j < 8; ++j) acc[i][j] = 0.f;

    for (int kk = 0; kk < 50; ++kk) {
        uint4 w0 = *(const uint4*)&sW[kk * 128 + c0];       // ds_read_b128
        uint4 w1 = *(const uint4*)&sW[kk * 128 + c0 + 4];   // ds_read_b128
#pragma unroll
        for (int i = 0; i < 8; ++i) {
            uint32 a = sX[(r0 + i) * 50 + kk];
            acc[i][0] = dot2f(a, w0.x, acc[i][0]);
            acc[i][1] = dot2f(a, w0.y, acc[i][1]);
            acc[i][2] = dot2f(a, w0.z, acc[i][2]);
            acc[i][3] = dot2f(a, w0.w, acc[i][3]);
            acc[i][4] = dot2f(a, w1.x, acc[i][4]);
            acc[i][5] = dot2f(a, w1.y, acc[i][5]);
            acc[i][6] = dot2f(a, w1.z, acc[i][6]);
            acc[i][7] = dot2f(a, w1.w, acc[i][7]);
        }
    }
#pragma unroll
    for (int i = 0; i < 8; ++i) {
        size_t node = node0 + r0 + i;
        if (node < (size_t)N) {
            float dv = dinv[node];
            uint32 p0 = pack_fp8x4(acc[i][0] * dv, acc[i][1] * dv,
                                   acc[i][2] * dv, acc[i][3] * dv);
            uint32 p1 = pack_fp8x4(acc[i][4] * dv, acc[i][5] * dv,
                                   acc[i][6] * dv, acc[i][7] * dv);
            *(uint2*)&xw8[node * 32 + (c0 >> 2)] = make_uint2(p0, p1);
        } else if (node == (size_t)N) {
            *(uint2*)&xw8[node * 32 + (c0 >> 2)] = make_uint2(0u, 0u);  // zero row
        }
    }
}

// ---------- agg1: h[n] (fp16) = relu(b1 + dinv[n] * sum_j xw8[src_j]) ----------

__global__ __launch_bounds__(256) void agg1(const uint32* __restrict__ xw8,
                                            const int* __restrict__ rowptr,
                                            const int* __restrict__ ep,
                                            const float* __restrict__ dinv,
                                            const float* __restrict__ b1,
                                            __half* __restrict__ h) {
    int node = blockIdx.x * 4 + (threadIdx.x >> 6);
    if (node >= N) return;
    int lane = threadIdx.x & 63;
    int hf = lane >> 5;      // which edge of the pair
    int q  = lane & 31;      // dword within 128B row -> dims q*4..q*4+3
    int beg = rowptr[node], end = rowptr[node + 1];   // cap, multiple of 8
    float a0 = 0.f, a1 = 0.f, a2 = 0.f, a3 = 0.f;
    for (int j = beg; j < end; j += 8) {
        int s0 = ep[j + hf];
        int s1 = ep[j + 2 + hf];
        int s2 = ep[j + 4 + hf];
        int s3 = ep[j + 6 + hf];
        uint32 v0 = xw8[(size_t)s0 * 32 + q];
        uint32 v1 = xw8[(size_t)s1 * 32 + q];
        uint32 v2 = xw8[(size_t)s2 * 32 + q];
        uint32 v3 = xw8[(size_t)s3 * 32 + q];
        acc_fp8x4(v0, a0, a1, a2, a3);
        acc_fp8x4(v1, a0, a1, a2, a3);
        acc_fp8x4(v2, a0, a1, a2, a3);
        acc_fp8x4(v3, a0, a1, a2, a3);
    }
    a0 += __shfl_xor(a0, 32);
    a1 += __shfl_xor(a1, 32);
    a2 += __shfl_xor(a2, 32);
    a3 += __shfl_xor(a3, 32);
    if (hf == 0) {
        float dv = dinv[node];
        float4 bb = *(const float4*)&b1[q * 4];
        float r0 = fmaxf(fmaf(dv, a0, bb.x), 0.f);
        float r1 = fmaxf(fmaf(dv, a1, bb.y), 0.f);
        float r2 = fmaxf(fmaf(dv, a2, bb.z), 0.f);
        float r3 = fmaxf(fmaf(dv, a3, bb.w), 0.f);
        union { __half2 h2[2]; uint2 u; } p;
        p.h2[0] = __floats2half2_rn(r0, r1);
        p.h2[1] = __floats2half2_rn(r2, r3);
        *(uint2*)&h[(size_t)node * HD + q * 4] = p.u;
    }
}

// ---------- GEMM2: xw2h[N+1,48] fp16 = dinv[n] * (h[N,128] @ W2[128,47]), col47=0 ----------

__global__ __launch_bounds__(256) void gemm2(const uint32* __restrict__ hh,
                                             const float* __restrict__ W2,
                                             const float* __restrict__ dinv,
                                             __half* __restrict__ xw2h) {
    __shared__ uint32 sW[64 * 48];     // 12.3 KB
    __shared__ uint32 sH[64 * 66];     // 16.9 KB (pad 66)
    int tx = threadIdx.x;
    size_t node0 = (size_t)blockIdx.x * 64;

    for (int i = tx; i < 64 * 48; i += 256) {
        int kk = i / 48, c = i - kk * 48;
        float a = 0.f, b = 0.f;
        if (c < C) {
            a = W2[(2 * kk) * C + c];
            b = W2[(2 * kk + 1) * C + c];
        }
        sW[i] = pk16(a, b);
    }
    for (int i = tx; i < 64 * 64; i += 256) {
        int row = i >> 6, kk = i & 63;
        size_t g = node0 * 64 + i;
        sH[row * 66 + kk] = (g < (size_t)N * 64) ? hh[g] : 0u;
    }
    __syncthreads();

    int c0 = (tx & 15) * 3;        // 0..45
    int nb = (tx >> 4) * 4;        // 0..60
    float acc[4][3] = {};
    for (int kk = 0; kk < 64; ++kk) {
        uint32 w0 = sW[kk * 48 + c0];
        uint32 w1 = sW[kk * 48 + c0 + 1];
        uint32 w2 = sW[kk * 48 + c0 + 2];
#pragma unroll
        for (int i = 0; i < 4; ++i) {
            uint32 a = sH[(nb + i) * 66 + kk];
            acc[i][0] = dot2f(a, w0, acc[i][0]);
            acc[i][1] = dot2f(a, w1, acc[i][1]);
            acc[i][2] = dot2f(a, w2, acc[i][2]);
        }
    }
#pragma unroll
    for (int i = 0; i < 4; ++i) {
        size_t node = node0 + nb + i;
        if (node < (size_t)N) {
            float dv = dinv[node];
#pragma unroll
            for (int jj = 0; jj < 3; ++jj) {
                // col 47 gets 0 (sW pad col is 0) -> true zero pad
                xw2h[node * C48 + c0 + jj] = __float2half_rn(acc[i][jj] * dv);
            }
        } else if (node == (size_t)N) {
#pragma unroll
            for (int jj = 0; jj < 3; ++jj)
                xw2h[node * C48 + c0 + jj] = __float2half_rn(0.f);  // zero row for pads
        }
    }
}

// ---------- agg2: out[n] = b2 + dinv[n] * sum_j xw2[src_j] ----------
// dword (=half2) gather: 24 lanes cover one 96B row exactly; 2 edges per step.

__global__ __launch_bounds__(256) void agg2(const uint32* __restrict__ xw2d,
                                            const int* __restrict__ rowptr,
                                            const int* __restrict__ ep,
                                            const float* __restrict__ dinv,
                                            const float* __restrict__ b2,
                                            float* __restrict__ out) {
    int node = blockIdx.x * 4 + (threadIdx.x >> 6);
    if (node >= N) return;
    int lane = threadIdx.x & 63;
    int hf = lane >> 5;      // which edge of the pair
    int q  = lane & 31;      // dword within row (only q<24 valid)
    bool act = q < 24;
    int beg = rowptr[node], end = rowptr[node + 1];   // cap, multiple of 8
    float a0 = 0.f, a1 = 0.f;
    for (int j = beg; j < end; j += 8) {
        int s0 = ep[j + hf];
        int s1 = ep[j + 2 + hf];
        int s2 = ep[j + 4 + hf];
        int s3 = ep[j + 6 + hf];
        if (act) {
            uint32 v0 = xw2d[(size_t)s0 * 24 + q];
            uint32 v1 = xw2d[(size_t)s1 * 24 + q];
            uint32 v2 = xw2d[(size_t)s2 * 24 + q];
            uint32 v3 = xw2d[(size_t)s3 * 24 + q];
            float2 f;
            f = __half22float2(*(const __half2*)&v0); a0 += f.x; a1 += f.y;
            f = __half22float2(*(const __half2*)&v1); a0 += f.x; a1 += f.y;
            f = __half22float2(*(const __half2*)&v2); a0 += f.x; a1 += f.y;
            f = __half22float2(*(const __half2*)&v3); a0 += f.x; a1 += f.y;
        }
    }
    a0 += __shfl_xor(a0, 32);
    a1 += __shfl_xor(a1, 32);
    if (hf == 0 && act) {
        float dv = dinv[node];
        int c = q * 2;
        out[(size_t)node * C + c] = fmaf(dv, a0, b2[c]);
        if (c + 1 < C) out[(size_t)node * C + c + 1] = fmaf(dv, a1, b2[c + 1]);
    }
}

extern "C" void kernel_launch(void* const* d_in, const int* in_sizes, int n_in,
                              void* d_out, int out_size, void* d_ws, size_t ws_size,
                              hipStream_t stream) {
    const float* x  = (const float*)d_in[0];
    const int*   ei = (const int*)d_in[1];
    const float* W1 = (const float*)d_in[2];
    const float* b1 = (const float*)d_in[3];
    const float* W2 = (const float*)d_in[4];
    const float* b2 = (const float*)d_in[5];
    float* out = (float*)d_out;

    size_t off = 0;
    auto alloc = [&](size_t bytes) {
        void* p = (char*)d_ws + off;
        off += (bytes + 255) & ~(size_t)255;
        return p;
    };
    int*    cnt       = (int*)alloc((size_t)N * 4);
    int*    rowptr    = (int*)alloc((size_t)(N + 1) * 4);
    int*    blockhist = (int*)alloc((size_t)NBUCK * ABLK * 4);
    int*    bcnt      = (int*)alloc((size_t)NBUCK * 4);
    int*    bbase     = (int*)alloc((size_t)(NBUCK + 1) * 4);
    uint32* pairs     = (uint32*)alloc((size_t)E * 4);
    int*    partials  = (int*)alloc(64 * 4);
    int*    pscan     = (int*)alloc(64 * 4);
    float*  dinv      = (float*)alloc((size_t)N * 4);
    int*    ep        = (int*)alloc((size_t)EN_CAP * 4);
    uint32* xw8       = (uint32*)alloc((size_t)(N + 1) * 32 * 4);   // fp8 [N+1][128]
    __half* hh        = (__half*)alloc((size_t)N * HD * 2);
    __half* xw2h      = (__half*)alloc((size_t)(N + 1) * C48 * 2);  // fp16 [N+1][48]
    (void)ws_size;

    bucket_hist<<<ABLK, 256, 0, stream>>>(ei + E, blockhist);
    scan_blocks<<<NBUCK, 256, 0, stream>>>(blockhist, bcnt);
    scan_buckets<<<1, 64, 0, stream>>>(bcnt, bbase);
    bucket_scatter<<<ABLK, 256, 0, stream>>>(ei, blockhist, bbase, pairs);
    bucket_count<<<NBUCK, 256, 0, stream>>>(pairs, bbase, cnt);
    scan_pass1<<<NB_SCAN, 256, 0, stream>>>(cnt, partials);
    scan_pass2<<<1, 64, 0, stream>>>(partials, pscan, rowptr);
    scan_pass3<<<NB_SCAN, 256, 0, stream>>>(cnt, pscan, rowptr, dinv, ep);
    bucket_place<<<NBUCK, 256, 0, stream>>>(pairs, bbase, rowptr, ep);

    gemm1<<<(N + 127) / 128, 256, 0, stream>>>(x, W1, dinv, xw8);
    agg1<<<(N + 3) / 4, 256, 0, stream>>>(xw8, rowptr, ep, dinv, b1, hh);
    gemm2<<<(N + 63) / 64, 256, 0, stream>>>((const uint32*)hh, W2, dinv, xw2h);
    agg2<<<(N + 3) / 4, 256, 0, stream>>>((const uint32*)xw2h, rowptr, ep, dinv, b2, out);
}

// Round 7
// 311.551 us; speedup vs baseline: 1.0639x; 1.0639x over previous
//
#include <hip/hip_runtime.h>
#include <hip/hip_fp16.h>

// GCN 2-layer inference, N=100000, E=1600000, F_IN=100, H=128, C=47.
// R10: gemm1 -> MFMA (16x16x32 f16, swapped operands). R9 post-mortem: 8x8
// VALU tile spilled (VGPR_Count 68 < ~90 needed) + 1.25M bank conflicts ->
// reverted. New gemm1: A := W1^T staged as frag-linear LDS (32KB, wave-linear
// ds_read_b128), B := x k-octets straight from global (2x dwordx4/lane,
// coalesced 128B-per-row), K padded 100->128 with zeros. C/D mapping
// (col=lane&15=node, row=(lane>>4)*4+reg=dim) gives each lane 4 consecutive
// dims of one node -> pack_fp8x4 directly, no transpose. 128 nodes/block,
// grid 782 (all-resident), ~90 VGPR, 5 blocks/CU.
// CSR build / agg1 / gemm2 / agg2 unchanged from R8 (325.8us, absmax 0.0078).

typedef unsigned int uint32;
typedef float f32x2 __attribute__((ext_vector_type(2)));
typedef __fp16 fp16x2 __attribute__((ext_vector_type(2)));
typedef _Float16 h2v __attribute__((ext_vector_type(2)));
typedef _Float16 f16x8 __attribute__((ext_vector_type(8)));
typedef float f32x4 __attribute__((ext_vector_type(4)));

constexpr int N    = 100000;
constexpr int E    = 1600000;
constexpr int FIN  = 100;
constexpr int HD   = 128;
constexpr int C    = 47;
constexpr int C48  = 48;
constexpr int EN_CAP = E + 8 * N;    // padded edge-slot upper bound
constexpr int SCAN_CHUNK = 2048;     // 256 threads * 8
constexpr int NB_SCAN = (N + SCAN_CHUNK - 1) / SCAN_CHUNK;  // 49

// bucketed CSR build
constexpr int NPB   = 512;                          // nodes per bucket (dst>>9)
constexpr int NBUCK = (N + NPB - 1) / NPB;          // 196
constexpr int ABLK  = 400;                          // A-phase blocks
constexpr int EPB   = E / ABLK;                     // 4000 edges per A-block

// ---------- fp8 / fp16 helpers ----------

__device__ __forceinline__ uint32 pack_fp8x4(float x, float y, float z, float w) {
    int r = __builtin_amdgcn_cvt_pk_fp8_f32(x, y, 0, false);   // bytes 0,1
    r = __builtin_amdgcn_cvt_pk_fp8_f32(z, w, r, true);        // bytes 2,3
    return (uint32)r;
}

__device__ __forceinline__ void acc_fp8x4(uint32 v, float& a0, float& a1,
                                          float& a2, float& a3) {
    f32x2 lo = __builtin_amdgcn_cvt_pk_f32_fp8((int)v, false);
    f32x2 hi = __builtin_amdgcn_cvt_pk_f32_fp8((int)v, true);
    a0 += lo[0]; a1 += lo[1]; a2 += hi[0]; a3 += hi[1];
}

__device__ __forceinline__ uint32 pk16(float a, float b) {
    union { fp16x2 h; uint32 u; } x;
    x.h = __builtin_amdgcn_cvt_pkrtz(a, b);    // v_cvt_pkrtz_f16_f32
    return x.u;
}

__device__ __forceinline__ float dot2f(uint32 a, uint32 b, float c) {
#if defined(__has_builtin) && __has_builtin(__builtin_amdgcn_fdot2)
    union { uint32 u; h2v h; } xa, xb; xa.u = a; xb.u = b;
    return __builtin_amdgcn_fdot2(xa.h, xb.h, c, false);
#else
    union { uint32 u; __half2 h; } xa, xb; xa.u = a; xb.u = b;
    float2 fa = __half22float2(xa.h), fb = __half22float2(xb.h);
    return fmaf(fa.y, fb.y, fmaf(fa.x, fb.x, c));
#endif
}

// ---------- bucketed CSR build (no global atomics) ----------

// A1: per-block bucket histogram -> blockhist[bucket][block]
__global__ __launch_bounds__(256) void bucket_hist(const int* __restrict__ dst,
                                                   int* __restrict__ blockhist) {
    __shared__ int h[NBUCK];
    int t = threadIdx.x, blk = blockIdx.x;
    for (int i = t; i < NBUCK; i += 256) h[i] = 0;
    __syncthreads();
    int base = blk * EPB;
    for (int i = t; i < EPB; i += 256)
        atomicAdd(&h[dst[base + i] >> 9], 1);
    __syncthreads();
    for (int i = t; i < NBUCK; i += 256) blockhist[i * ABLK + blk] = h[i];
}

// S1a: per-bucket exclusive scan over the 400 block entries (in place);
// bucket total -> bcnt[b]
__global__ __launch_bounds__(256) void scan_blocks(int* __restrict__ blockhist,
                                                   int* __restrict__ bcnt) {
    __shared__ int sm[512];
    int b = blockIdx.x, t = threadIdx.x;
    int v0 = (t       < ABLK) ? blockhist[b * ABLK + t] : 0;
    int v1 = (t + 256 < ABLK) ? blockhist[b * ABLK + t + 256] : 0;
    sm[t] = v0; sm[t + 256] = v1;
    __syncthreads();
    for (int off = 1; off < 512; off <<= 1) {
        int o0 = sm[t], o1 = sm[t + 256];
        int a0 = (t >= off) ? sm[t - off] : 0;
        int a1 = (t + 256 >= off) ? sm[t + 256 - off] : 0;
        __syncthreads();
        sm[t] = o0 + a0; sm[t + 256] = o1 + a1;
        __syncthreads();
    }
    if (t < ABLK)       blockhist[b * ABLK + t]       = sm[t] - v0;        // exclusive
    if (t + 256 < ABLK) blockhist[b * ABLK + t + 256] = sm[t + 256] - v1;
    if (t == 0) bcnt[b] = sm[ABLK - 1];
}

// S1b: exclusive scan over 196 bucket totals
__global__ void scan_buckets(const int* __restrict__ bcnt, int* __restrict__ bbase) {
    if (threadIdx.x == 0) {
        int run = 0;
        for (int i = 0; i < NBUCK; ++i) { bbase[i] = run; run += bcnt[i]; }
        bbase[NBUCK] = run;   // == E
    }
}

// A2: place packed (dstLocal<<20 | src) into dense bucket segments
__global__ __launch_bounds__(256) void bucket_scatter(const int* __restrict__ ei,
                                                      const int* __restrict__ blockhist,
                                                      const int* __restrict__ bbase,
                                                      uint32* __restrict__ pairs) {
    __shared__ int baseL[NBUCK];
    __shared__ int cur[NBUCK];
    int t = threadIdx.x, blk = blockIdx.x;
    for (int i = t; i < NBUCK; i += 256) {
        baseL[i] = bbase[i] + blockhist[i * ABLK + blk];
        cur[i] = 0;
    }
    __syncthreads();
    int base = blk * EPB;
    for (int i = t; i < EPB; i += 256) {
        int s = ei[base + i];
        int d = ei[E + base + i];
        int b = d >> 9;
        int off = atomicAdd(&cur[b], 1);
        pairs[baseL[b] + off] = (uint32)s | ((uint32)(d & (NPB - 1)) << 20);
    }
}

// B1: per-bucket node degree count (LDS atomics) -> cnt[] (1 = self loop)
__global__ __launch_bounds__(256) void bucket_count(const uint32* __restrict__ pairs,
                                                    const int* __restrict__ bbase,
                                                    int* __restrict__ cnt) {
    __shared__ int c[NPB];
    int b = blockIdx.x, t = threadIdx.x;
    for (int i = t; i < NPB; i += 256) c[i] = 1;   // self loop
    __syncthreads();
    int beg = bbase[b], end = bbase[b + 1];
    for (int i = beg + t; i < end; i += 256)
        atomicAdd(&c[pairs[i] >> 20], 1);
    __syncthreads();
    int node0 = b * NPB;
    for (int i = t; i < NPB; i += 256) {
        int n = node0 + i;
        if (n < N) cnt[n] = c[i];
    }
}

// B2: per-bucket slot placement; ep writes stay inside the bucket's CSR range
__global__ __launch_bounds__(256) void bucket_place(const uint32* __restrict__ pairs,
                                                    const int* __restrict__ bbase,
                                                    const int* __restrict__ rowptr,
                                                    int* __restrict__ ep) {
    __shared__ int rowL[NPB];
    __shared__ int cur[NPB];
    int b = blockIdx.x, t = threadIdx.x;
    int node0 = b * NPB;
    for (int i = t; i < NPB; i += 256) {
        int n = node0 + i;
        rowL[i] = (n < N) ? rowptr[n] : 0;
        cur[i] = 1;   // slot 0 = self loop (written by scan_pass3)
    }
    __syncthreads();
    int beg = bbase[b], end = bbase[b + 1];
    for (int i = beg + t; i < end; i += 256) {
        uint32 p = pairs[i];
        int dl = p >> 20;
        int slot = atomicAdd(&cur[dl], 1);
        ep[rowL[dl] + slot] = (int)(p & 0xFFFFF);
    }
}

// ---------- global scan over node capacities ----------

// sums CAPACITIES: cap = deg rounded up to multiple of 8
__global__ void scan_pass1(const int* __restrict__ cnt, int* __restrict__ partials) {
    int t = threadIdx.x, b = blockIdx.x;
    int base = b * SCAN_CHUNK + t * 8;
    int s = 0;
#pragma unroll
    for (int i = 0; i < 8; ++i) {
        int idx = base + i;
        if (idx < N) s += (cnt[idx] + 7) & ~7;
    }
    __shared__ int sm[256];
    sm[t] = s;
    __syncthreads();
    for (int off = 128; off > 0; off >>= 1) {
        if (t < off) sm[t] += sm[t + off];
        __syncthreads();
    }
    if (t == 0) partials[b] = sm[0];
}

__global__ void scan_pass2(const int* __restrict__ partials, int* __restrict__ pscan,
                           int* __restrict__ rowptr) {
    if (threadIdx.x == 0) {
        int run = 0;
        for (int i = 0; i < NB_SCAN; ++i) { pscan[i] = run; run += partials[i]; }
        rowptr[N] = run;   // padded total, <= E + 8N
    }
}

// rowptr (cap-based) + dinv + self-loop slot + pad slots (src=N -> zero row)
__global__ void scan_pass3(const int* __restrict__ cnt, const int* __restrict__ pscan,
                           int* __restrict__ rowptr, float* __restrict__ dinv,
                           int* __restrict__ ep) {
    int t = threadIdx.x, b = blockIdx.x;
    int base = b * SCAN_CHUNK + t * 8;
    int v[8];
    int s = 0;
#pragma unroll
    for (int i = 0; i < 8; ++i) {
        int idx = base + i;
        v[i] = (idx < N) ? cnt[idx] : 0;
        s += (v[i] + 7) & ~7;
    }
    __shared__ int sm[256];
    sm[t] = s;
    __syncthreads();
    for (int off = 1; off < 256; off <<= 1) {
        int tv = (t >= off) ? sm[t - off] : 0;
        __syncthreads();
        sm[t] += tv;
        __syncthreads();
    }
    int excl = sm[t] - s + pscan[b];
#pragma unroll
    for (int i = 0; i < 8; ++i) {
        int idx = base + i;
        if (idx < N) {
            int cap = (v[i] + 7) & ~7;
            rowptr[idx] = excl;
            ep[excl] = idx;                  // self loop at slot 0
            dinv[idx] = rsqrtf((float)v[i]); // true degree (>=1)
            for (int k = v[i]; k < cap; ++k) ep[excl + k] = N;  // pads -> zero row
            excl += cap;
        }
    }
}

// ---------- GEMM1 (MFMA): xw8[N+1,32 dwords] fp8 = dinv[n]*(x @ W1) ----------
// D = A*B with A := W1^T (16n x 32k frags from LDS), B := x rows (32k x 16
// nodes, global dwordx4 + pkrtz). C/D: col=lane&15=node, row=(lane>>4)*4+reg
// = dim -> lane holds 4 consecutive dims of one node -> pack_fp8x4 direct.
// 128 nodes/block (4 waves x 2 node-tiles), K 100 zero-padded to 128.

__global__ __launch_bounds__(256) void gemm1(const float* __restrict__ x,
                                             const float* __restrict__ W1,
                                             const float* __restrict__ dinv,
                                             uint32* __restrict__ xw8) {
    __shared__ uint32 sA[8192];   // 32 KB, frag-linear: [(nt*4+ks)*256 + l*4 + d]
    int tx = threadIdx.x;

    for (int idx = tx; idx < 8192; idx += 256) {
        int slot = idx >> 8;               // nt*4 + ks
        int rem  = idx & 255;
        int l = rem >> 2, d = rem & 3;
        int nt = slot >> 2, ks = slot & 3;
        int n = nt * 16 + (l & 15);
        int k = ks * 32 + (l >> 4) * 8 + 2 * d;
        float va = (k < FIN)     ? W1[k * HD + n]       : 0.f;
        float vb = (k + 1 < FIN) ? W1[(k + 1) * HD + n] : 0.f;
        sA[idx] = pk16(va, vb);
    }
    __syncthreads();

    int l = tx & 63, w = tx >> 6;
    int m = l & 15, oct = l >> 4;
    size_t node0 = (size_t)blockIdx.x * 128 + (size_t)w * 32;
    size_t nA = node0 + m;          // node-tile 0
    size_t nB = node0 + 16 + m;     // node-tile 1

    f32x4 acc0[8], acc1[8];
#pragma unroll
    for (int nt = 0; nt < 8; ++nt) {
        acc0[nt] = (f32x4){0.f, 0.f, 0.f, 0.f};
        acc1[nt] = (f32x4){0.f, 0.f, 0.f, 0.f};
    }

#pragma unroll
    for (int ks = 0; ks < 4; ++ks) {
        int k0 = ks * 32 + oct * 8;
        float4 fa0 = make_float4(0.f, 0.f, 0.f, 0.f), fa1 = fa0;
        float4 fb0 = make_float4(0.f, 0.f, 0.f, 0.f), fb1 = fb0;
        if (nA < (size_t)N) {
            const float* xr = x + nA * FIN;
            if (k0 < FIN)     fa0 = *(const float4*)(xr + k0);
            if (k0 + 4 < FIN) fa1 = *(const float4*)(xr + k0 + 4);
        }
        if (nB < (size_t)N) {
            const float* xr = x + nB * FIN;
            if (k0 < FIN)     fb0 = *(const float4*)(xr + k0);
            if (k0 + 4 < FIN) fb1 = *(const float4*)(xr + k0 + 4);
        }
        union { uint4 u; f16x8 h; } b0, b1;
        b0.u = make_uint4(pk16(fa0.x, fa0.y), pk16(fa0.z, fa0.w),
                          pk16(fa1.x, fa1.y), pk16(fa1.z, fa1.w));
        b1.u = make_uint4(pk16(fb0.x, fb0.y), pk16(fb0.z, fb0.w),
                          pk16(fb1.x, fb1.y), pk16(fb1.z, fb1.w));
#pragma unroll
        for (int nt = 0; nt < 8; ++nt) {
            union { uint4 u; f16x8 h; } a;
            a.u = *(const uint4*)&sA[(nt * 4 + ks) * 256 + l * 4];
            acc0[nt] = __builtin_amdgcn_mfma_f32_16x16x32_f16(a.h, b0.h, acc0[nt], 0, 0, 0);
            acc1[nt] = __builtin_amdgcn_mfma_f32_16x16x32_f16(a.h, b1.h, acc1[nt], 0, 0, 0);
        }
    }

    if (nA <= (size_t)N) {
        float dv = (nA < (size_t)N) ? dinv[nA] : 0.f;
#pragma unroll
        for (int nt = 0; nt < 8; ++nt) {
            f32x4 v = acc0[nt];
            uint32 p = (nA < (size_t)N)
                ? pack_fp8x4(v[0] * dv, v[1] * dv, v[2] * dv, v[3] * dv) : 0u;
            xw8[nA * 32 + nt * 4 + oct] = p;
        }
    }
    if (nB <= (size_t)N) {
        float dv = (nB < (size_t)N) ? dinv[nB] : 0.f;
#pragma unroll
        for (int nt = 0; nt < 8; ++nt) {
            f32x4 v = acc1[nt];
            uint32 p = (nB < (size_t)N)
                ? pack_fp8x4(v[0] * dv, v[1] * dv, v[2] * dv, v[3] * dv) : 0u;
            xw8[nB * 32 + nt * 4 + oct] = p;
        }
    }
}

// ---------- agg1: h[n] (fp16) = relu(b1 + dinv[n] * sum_j xw8[src_j]) ----------

__global__ __launch_bounds__(256) void agg1(const uint32* __restrict__ xw8,
                                            const int* __restrict__ rowptr,
                                            const int* __restrict__ ep,
                                            const float* __restrict__ dinv,
                                            const float* __restrict__ b1,
                                            __half* __restrict__ h) {
    int node = blockIdx.x * 4 + (threadIdx.x >> 6);
    if (node >= N) return;
    int lane = threadIdx.x & 63;
    int hf = lane >> 5;      // which edge of the pair
    int q  = lane & 31;      // dword within 128B row -> dims q*4..q*4+3
    int beg = rowptr[node], end = rowptr[node + 1];   // cap, multiple of 8
    float a0 = 0.f, a1 = 0.f, a2 = 0.f, a3 = 0.f;
    for (int j = beg; j < end; j += 8) {
        int s0 = ep[j + hf];
        int s1 = ep[j + 2 + hf];
        int s2 = ep[j + 4 + hf];
        int s3 = ep[j + 6 + hf];
        uint32 v0 = xw8[(size_t)s0 * 32 + q];
        uint32 v1 = xw8[(size_t)s1 * 32 + q];
        uint32 v2 = xw8[(size_t)s2 * 32 + q];
        uint32 v3 = xw8[(size_t)s3 * 32 + q];
        acc_fp8x4(v0, a0, a1, a2, a3);
        acc_fp8x4(v1, a0, a1, a2, a3);
        acc_fp8x4(v2, a0, a1, a2, a3);
        acc_fp8x4(v3, a0, a1, a2, a3);
    }
    a0 += __shfl_xor(a0, 32);
    a1 += __shfl_xor(a1, 32);
    a2 += __shfl_xor(a2, 32);
    a3 += __shfl_xor(a3, 32);
    if (hf == 0) {
        float dv = dinv[node];
        float4 bb = *(const float4*)&b1[q * 4];
        float r0 = fmaxf(fmaf(dv, a0, bb.x), 0.f);
        float r1 = fmaxf(fmaf(dv, a1, bb.y), 0.f);
        float r2 = fmaxf(fmaf(dv, a2, bb.z), 0.f);
        float r3 = fmaxf(fmaf(dv, a3, bb.w), 0.f);
        union { __half2 h2[2]; uint2 u; } p;
        p.h2[0] = __floats2half2_rn(r0, r1);
        p.h2[1] = __floats2half2_rn(r2, r3);
        *(uint2*)&h[(size_t)node * HD + q * 4] = p.u;
    }
}

// ---------- GEMM2: xw2h[N+1,48] fp16 = dinv[n] * (h[N,128] @ W2[128,47]), col47=0 ----------

__global__ __launch_bounds__(256) void gemm2(const uint32* __restrict__ hh,
                                             const float* __restrict__ W2,
                                             const float* __restrict__ dinv,
                                             __half* __restrict__ xw2h) {
    __shared__ uint32 sW[64 * 48];     // 12.3 KB
    __shared__ uint32 sH[64 * 66];     // 16.9 KB (pad 66)
    int tx = threadIdx.x;
    size_t node0 = (size_t)blockIdx.x * 64;

    for (int i = tx; i < 64 * 48; i += 256) {
        int kk = i / 48, c = i - kk * 48;
        float a = 0.f, b = 0.f;
        if (c < C) {
            a = W2[(2 * kk) * C + c];
            b = W2[(2 * kk + 1) * C + c];
        }
        sW[i] = pk16(a, b);
    }
    for (int i = tx; i < 64 * 64; i += 256) {
        int row = i >> 6, kk = i & 63;
        size_t g = node0 * 64 + i;
        sH[row * 66 + kk] = (g < (size_t)N * 64) ? hh[g] : 0u;
    }
    __syncthreads();

    int c0 = (tx & 15) * 3;        // 0..45
    int nb = (tx >> 4) * 4;        // 0..60
    float acc[4][3] = {};
    for (int kk = 0; kk < 64; ++kk) {
        uint32 w0 = sW[kk * 48 + c0];
        uint32 w1 = sW[kk * 48 + c0 + 1];
        uint32 w2 = sW[kk * 48 + c0 + 2];
#pragma unroll
        for (int i = 0; i < 4; ++i) {
            uint32 a = sH[(nb + i) * 66 + kk];
            acc[i][0] = dot2f(a, w0, acc[i][0]);
            acc[i][1] = dot2f(a, w1, acc[i][1]);
            acc[i][2] = dot2f(a, w2, acc[i][2]);
        }
    }
#pragma unroll
    for (int i = 0; i < 4; ++i) {
        size_t node = node0 + nb + i;
        if (node < (size_t)N) {
            float dv = dinv[node];
#pragma unroll
            for (int jj = 0; jj < 3; ++jj) {
                // col 47 gets 0 (sW pad col is 0) -> true zero pad
                xw2h[node * C48 + c0 + jj] = __float2half_rn(acc[i][jj] * dv);
            }
        } else if (node == (size_t)N) {
#pragma unroll
            for (int jj = 0; jj < 3; ++jj)
                xw2h[node * C48 + c0 + jj] = __float2half_rn(0.f);  // zero row for pads
        }
    }
}

// ---------- agg2: out[n] = b2 + dinv[n] * sum_j xw2[src_j] ----------
// dword (=half2) gather: 24 lanes cover one 96B row exactly; 2 edges per step.

__global__ __launch_bounds__(256) void agg2(const uint32* __restrict__ xw2d,
                                            const int* __restrict__ rowptr,
                                            const int* __restrict__ ep,
                                            const float* __restrict__ dinv,
                                            const float* __restrict__ b2,
                                            float* __restrict__ out) {
    int node = blockIdx.x * 4 + (threadIdx.x >> 6);
    if (node >= N) return;
    int lane = threadIdx.x & 63;
    int hf = lane >> 5;      // which edge of the pair
    int q  = lane & 31;      // dword within row (only q<24 valid)
    bool act = q < 24;
    int beg = rowptr[node], end = rowptr[node + 1];   // cap, multiple of 8
    float a0 = 0.f, a1 = 0.f;
    for (int j = beg; j < end; j += 8) {
        int s0 = ep[j + hf];
        int s1 = ep[j + 2 + hf];
        int s2 = ep[j + 4 + hf];
        int s3 = ep[j + 6 + hf];
        if (act) {
            uint32 v0 = xw2d[(size_t)s0 * 24 + q];
            uint32 v1 = xw2d[(size_t)s1 * 24 + q];
            uint32 v2 = xw2d[(size_t)s2 * 24 + q];
            uint32 v3 = xw2d[(size_t)s3 * 24 + q];
            float2 f;
            f = __half22float2(*(const __half2*)&v0); a0 += f.x; a1 += f.y;
            f = __half22float2(*(const __half2*)&v1); a0 += f.x; a1 += f.y;
            f = __half22float2(*(const __half2*)&v2); a0 += f.x; a1 += f.y;
            f = __half22float2(*(const __half2*)&v3); a0 += f.x; a1 += f.y;
        }
    }
    a0 += __shfl_xor(a0, 32);
    a1 += __shfl_xor(a1, 32);
    if (hf == 0 && act) {
        float dv = dinv[node];
        int c = q * 2;
        out[(size_t)node * C + c] = fmaf(dv, a0, b2[c]);
        if (c + 1 < C) out[(size_t)node * C + c + 1] = fmaf(dv, a1, b2[c + 1]);
    }
}

extern "C" void kernel_launch(void* const* d_in, const int* in_sizes, int n_in,
                              void* d_out, int out_size, void* d_ws, size_t ws_size,
                              hipStream_t stream) {
    const float* x  = (const float*)d_in[0];
    const int*   ei = (const int*)d_in[1];
    const float* W1 = (const float*)d_in[2];
    const float* b1 = (const float*)d_in[3];
    const float* W2 = (const float*)d_in[4];
    const float* b2 = (const float*)d_in[5];
    float* out = (float*)d_out;

    size_t off = 0;
    auto alloc = [&](size_t bytes) {
        void* p = (char*)d_ws + off;
        off += (bytes + 255) & ~(size_t)255;
        return p;
    };
    int*    cnt       = (int*)alloc((size_t)N * 4);
    int*    rowptr    = (int*)alloc((size_t)(N + 1) * 4);
    int*    blockhist = (int*)alloc((size_t)NBUCK * ABLK * 4);
    int*    bcnt      = (int*)alloc((size_t)NBUCK * 4);
    int*    bbase     = (int*)alloc((size_t)(NBUCK + 1) * 4);
    uint32* pairs     = (uint32*)alloc((size_t)E * 4);
    int*    partials  = (int*)alloc(64 * 4);
    int*    pscan     = (int*)alloc(64 * 4);
    float*  dinv      = (float*)alloc((size_t)N * 4);
    int*    ep        = (int*)alloc((size_t)EN_CAP * 4);
    uint32* xw8       = (uint32*)alloc((size_t)(N + 1) * 32 * 4);   // fp8 [N+1][128]
    __half* hh        = (__half*)alloc((size_t)N * HD * 2);
    __half* xw2h      = (__half*)alloc((size_t)(N + 1) * C48 * 2);  // fp16 [N+1][48]
    (void)ws_size;

    bucket_hist<<<ABLK, 256, 0, stream>>>(ei + E, blockhist);
    scan_blocks<<<NBUCK, 256, 0, stream>>>(blockhist, bcnt);
    scan_buckets<<<1, 64, 0, stream>>>(bcnt, bbase);
    bucket_scatter<<<ABLK, 256, 0, stream>>>(ei, blockhist, bbase, pairs);
    bucket_count<<<NBUCK, 256, 0, stream>>>(pairs, bbase, cnt);
    scan_pass1<<<NB_SCAN, 256, 0, stream>>>(cnt, partials);
    scan_pass2<<<1, 64, 0, stream>>>(partials, pscan, rowptr);
    scan_pass3<<<NB_SCAN, 256, 0, stream>>>(cnt, pscan, rowptr, dinv, ep);
    bucket_place<<<NBUCK, 256, 0, stream>>>(pairs, bbase, rowptr, ep);

    gemm1<<<(N + 128) / 128, 256, 0, stream>>>(x, W1, dinv, xw8);   // 782: covers node N
    agg1<<<(N + 3) / 4, 256, 0, stream>>>(xw8, rowptr, ep, dinv, b1, hh);
    gemm2<<<(N + 63) / 64, 256, 0, stream>>>((const uint32*)hh, W2, dinv, xw2h);
    agg2<<<(N + 3) / 4, 256, 0, stream>>>((const uint32*)xw2h, rowptr, ep, dinv, b2, out);
}